// Round 3
// baseline (1488.435 us; speedup 1.0000x reference)
//
#include <hip/hip_runtime.h>

// Problem constants
#define SEQ   2048
#define INF_  512          // IN dim
#define HQ    16           // query heads
#define KVH   4            // kv heads
#define DH    64           // head dim
#define NQ    (HQ*DH)      // 1024
#define NKV   (KVH*DH)     // 256
#define NQKV  (NQ + 2*NKV) // 1536
#define OUTD  512

// ---------------------------------------------------------------------------
// GEMM 1: fused QKV projection.  C[s][n] = sum_k x[s][k] * W[n][k]
// x fp32 [SEQ][INF_]; W in {Wq,Wk,Wv} selected by column block; out fp32
// QKV [SEQ][NQKV].  Tiles 64x64, BK=32, 256 threads, 4x4 per thread.
// ---------------------------------------------------------------------------
#define BM 64
#define BN 64
#define BK 32

__global__ __launch_bounds__(256) void gemm_qkv(
    const float* __restrict__ x,
    const float* __restrict__ Wq,
    const float* __restrict__ Wk,
    const float* __restrict__ Wv,
    float* __restrict__ QKV)
{
    __shared__ float As[BM][BK + 1];
    __shared__ float Bs[BN][BK + 1];

    const int m0 = blockIdx.x * BM;
    const int n0 = blockIdx.y * BN;

    const float* Bp;
    int brow0;
    if (n0 < NQ)            { Bp = Wq; brow0 = n0; }
    else if (n0 < NQ + NKV) { Bp = Wk; brow0 = n0 - NQ; }
    else                    { Bp = Wv; brow0 = n0 - NQ - NKV; }

    const int tid = threadIdx.x;
    const int lr = tid >> 2;           // 0..63  (tile row for loads)
    const int lc = (tid & 3) * 8;      // 0,8,16,24 (k-chunk)
    const int ty4 = (tid >> 4) * 4;    // 0..60
    const int tx4 = (tid & 15) * 4;    // 0..60

    float acc[4][4] = {};

    for (int kb = 0; kb < INF_; kb += BK) {
        const float* ap = x  + (size_t)(m0 + lr) * INF_ + kb + lc;
        const float* bp = Bp + (size_t)(brow0 + lr) * INF_ + kb + lc;
        float4 a0 = *(const float4*)(ap);
        float4 a1 = *(const float4*)(ap + 4);
        float4 b0 = *(const float4*)(bp);
        float4 b1 = *(const float4*)(bp + 4);
        __syncthreads();
        As[lr][lc]     = a0.x; As[lr][lc + 1] = a0.y;
        As[lr][lc + 2] = a0.z; As[lr][lc + 3] = a0.w;
        As[lr][lc + 4] = a1.x; As[lr][lc + 5] = a1.y;
        As[lr][lc + 6] = a1.z; As[lr][lc + 7] = a1.w;
        Bs[lr][lc]     = b0.x; Bs[lr][lc + 1] = b0.y;
        Bs[lr][lc + 2] = b0.z; Bs[lr][lc + 3] = b0.w;
        Bs[lr][lc + 4] = b1.x; Bs[lr][lc + 5] = b1.y;
        Bs[lr][lc + 6] = b1.z; Bs[lr][lc + 7] = b1.w;
        __syncthreads();
#pragma unroll
        for (int kk = 0; kk < BK; kk++) {
            float a0s = As[ty4 + 0][kk], a1s = As[ty4 + 1][kk];
            float a2s = As[ty4 + 2][kk], a3s = As[ty4 + 3][kk];
            float b0s = Bs[tx4 + 0][kk], b1s = Bs[tx4 + 1][kk];
            float b2s = Bs[tx4 + 2][kk], b3s = Bs[tx4 + 3][kk];
            acc[0][0] += a0s*b0s; acc[0][1] += a0s*b1s; acc[0][2] += a0s*b2s; acc[0][3] += a0s*b3s;
            acc[1][0] += a1s*b0s; acc[1][1] += a1s*b1s; acc[1][2] += a1s*b2s; acc[1][3] += a1s*b3s;
            acc[2][0] += a2s*b0s; acc[2][1] += a2s*b1s; acc[2][2] += a2s*b2s; acc[2][3] += a2s*b3s;
            acc[3][0] += a3s*b0s; acc[3][1] += a3s*b1s; acc[3][2] += a3s*b2s; acc[3][3] += a3s*b3s;
        }
    }

#pragma unroll
    for (int i = 0; i < 4; i++) {
        float4 v = make_float4(acc[i][0], acc[i][1], acc[i][2], acc[i][3]);
        *(float4*)(QKV + (size_t)(m0 + ty4 + i) * NQKV + n0 + tx4) = v;
    }
}

// ---------------------------------------------------------------------------
// Attention: flash-style, one block per (q-tile of 32 rows, query head h).
// Loops kv head g=0..3 inside, averaging (1/4 * softmax(QK^T/8) V) into Ofin.
// fp32 in/out (QKV ws -> Oh ws).  256 threads: thread owns row i=tid/8 and an
// 8-wide slice jd0=(tid%8)*8 (cols in score phase, dims in PV phase).
// ---------------------------------------------------------------------------
#define QT 32
#define TT 64

__global__ __launch_bounds__(256) void attn_kernel(
    const float* __restrict__ QKV, float* __restrict__ Oh)
{
    __shared__ __align__(16) float Qs [QT][68];
    __shared__ __align__(16) float Ps [QT][68];
    __shared__ __align__(16) float KsT[TT][68];   // KsT[d][j]
    __shared__ __align__(16) float Vs [TT][68];   // Vs[j][d]

    const int qt = (int)(gridDim.x - 1u - blockIdx.x);  // heavy tiles first
    const int h  = blockIdx.y;
    const int q0 = qt * QT;
    const int tid = threadIdx.x;
    const int i   = tid >> 3;          // 0..31 row in q-tile
    const int jd0 = (tid & 7) * 8;     // 8-wide slice

    {
        const float* src = QKV + (size_t)(q0 + i) * NQKV + h * DH + jd0;
        *(float4*)&Qs[i][jd0]     = *(const float4*)(src);
        *(float4*)&Qs[i][jd0 + 4] = *(const float4*)(src + 4);
    }

    float Ofin[8] = {};

    for (int g = 0; g < KVH; g++) {
        float m = -INFINITY, l = 0.f;
        float Oacc[8] = {};

        for (int t0 = 0; t0 < q0 + QT; t0 += TT) {
            __syncthreads();   // prior PV reads of Vs/Ps done before overwrite
            {
                const int j = tid >> 2;            // 0..63
                const int c = (tid & 3) * 16;      // 0,16,32,48
                const float* kbase = QKV + (size_t)(t0 + j) * NQKV + NQ + g * DH + c;
                const float* vbase = kbase + NKV;
                float kr[16];
                *(float4*)&kr[0]  = *(const float4*)(kbase);
                *(float4*)&kr[4]  = *(const float4*)(kbase + 4);
                *(float4*)&kr[8]  = *(const float4*)(kbase + 8);
                *(float4*)&kr[12] = *(const float4*)(kbase + 12);
#pragma unroll
                for (int mm = 0; mm < 16; mm++) KsT[c + mm][j] = kr[mm];
                *(float4*)&Vs[j][c]      = *(const float4*)(vbase);
                *(float4*)&Vs[j][c + 4]  = *(const float4*)(vbase + 4);
                *(float4*)&Vs[j][c + 8]  = *(const float4*)(vbase + 8);
                *(float4*)&Vs[j][c + 12] = *(const float4*)(vbase + 12);
            }
            __syncthreads();

            float sc[8] = {};
#pragma unroll
            for (int d4 = 0; d4 < DH; d4 += 4) {
                float4 qv = *(const float4*)&Qs[i][d4];
#pragma unroll
                for (int dd = 0; dd < 4; dd++) {
                    float qd = (dd == 0) ? qv.x : (dd == 1) ? qv.y : (dd == 2) ? qv.z : qv.w;
                    float4 k0 = *(const float4*)&KsT[d4 + dd][jd0];
                    float4 k1 = *(const float4*)&KsT[d4 + dd][jd0 + 4];
                    sc[0] += qd * k0.x; sc[1] += qd * k0.y; sc[2] += qd * k0.z; sc[3] += qd * k0.w;
                    sc[4] += qd * k1.x; sc[5] += qd * k1.y; sc[6] += qd * k1.z; sc[7] += qd * k1.w;
                }
            }

            float mx = -INFINITY;
#pragma unroll
            for (int jj = 0; jj < 8; jj++) {
                int col = t0 + jd0 + jj;
                sc[jj] = (col <= q0 + i) ? sc[jj] * 0.125f : -INFINITY;
                mx = fmaxf(mx, sc[jj]);
            }
            mx = fmaxf(mx, __shfl_xor(mx, 1));
            mx = fmaxf(mx, __shfl_xor(mx, 2));
            mx = fmaxf(mx, __shfl_xor(mx, 4));

            float mnew  = fmaxf(m, mx);
            float alpha = __expf(m - mnew);       // m=-inf first tile -> 0
            float rs = 0.f;
            float p[8];
#pragma unroll
            for (int jj = 0; jj < 8; jj++) {
                p[jj] = __expf(sc[jj] - mnew);    // masked -> exp(-inf)=0
                rs += p[jj];
            }
            rs += __shfl_xor(rs, 1);
            rs += __shfl_xor(rs, 2);
            rs += __shfl_xor(rs, 4);
            l = l * alpha + rs;
            m = mnew;

            *(float4*)&Ps[i][jd0]     = make_float4(p[0], p[1], p[2], p[3]);
            *(float4*)&Ps[i][jd0 + 4] = make_float4(p[4], p[5], p[6], p[7]);
#pragma unroll
            for (int dd = 0; dd < 8; dd++) Oacc[dd] *= alpha;
            __syncthreads();

#pragma unroll 4
            for (int j = 0; j < TT; j++) {
                float pj = Ps[i][j];
                float4 v0 = *(const float4*)&Vs[j][jd0];
                float4 v1 = *(const float4*)&Vs[j][jd0 + 4];
                Oacc[0] += pj * v0.x; Oacc[1] += pj * v0.y;
                Oacc[2] += pj * v0.z; Oacc[3] += pj * v0.w;
                Oacc[4] += pj * v1.x; Oacc[5] += pj * v1.y;
                Oacc[6] += pj * v1.z; Oacc[7] += pj * v1.w;
            }
        }

        float invl = 0.25f / l;   // l>0: tile t0=0 always has col 0 unmasked
#pragma unroll
        for (int dd = 0; dd < 8; dd++) Ofin[dd] += Oacc[dd] * invl;
    }

    float* dst = Oh + (size_t)(q0 + i) * NQ + h * DH + jd0;
    *(float4*)(dst)     = make_float4(Ofin[0], Ofin[1], Ofin[2], Ofin[3]);
    *(float4*)(dst + 4) = make_float4(Ofin[4], Ofin[5], Ofin[6], Ofin[7]);
}

// ---------------------------------------------------------------------------
// GEMM 2: out[s][o] = sum_j Oh[s][j] * Wo[o][j].  All fp32.
// ---------------------------------------------------------------------------
__global__ __launch_bounds__(256) void gemm_out(
    const float* __restrict__ A,
    const float* __restrict__ Wo,
    float* __restrict__ C)
{
    __shared__ float As[BM][BK + 1];
    __shared__ float Bs[BN][BK + 1];

    const int m0 = blockIdx.x * BM;
    const int n0 = blockIdx.y * BN;
    const int tid = threadIdx.x;
    const int lr = tid >> 2;
    const int lc = (tid & 3) * 8;
    const int ty4 = (tid >> 4) * 4;
    const int tx4 = (tid & 15) * 4;

    float acc[4][4] = {};

    for (int kb = 0; kb < NQ; kb += BK) {
        const float* ap = A  + (size_t)(m0 + lr) * NQ + kb + lc;
        const float* bp = Wo + (size_t)(n0 + lr) * NQ + kb + lc;
        float4 a0 = *(const float4*)(ap);
        float4 a1 = *(const float4*)(ap + 4);
        float4 b0 = *(const float4*)(bp);
        float4 b1 = *(const float4*)(bp + 4);
        __syncthreads();
        As[lr][lc]     = a0.x; As[lr][lc + 1] = a0.y;
        As[lr][lc + 2] = a0.z; As[lr][lc + 3] = a0.w;
        As[lr][lc + 4] = a1.x; As[lr][lc + 5] = a1.y;
        As[lr][lc + 6] = a1.z; As[lr][lc + 7] = a1.w;
        Bs[lr][lc]     = b0.x; Bs[lr][lc + 1] = b0.y;
        Bs[lr][lc + 2] = b0.z; Bs[lr][lc + 3] = b0.w;
        Bs[lr][lc + 4] = b1.x; Bs[lr][lc + 5] = b1.y;
        Bs[lr][lc + 6] = b1.z; Bs[lr][lc + 7] = b1.w;
        __syncthreads();
#pragma unroll
        for (int kk = 0; kk < BK; kk++) {
            float a0s = As[ty4 + 0][kk], a1s = As[ty4 + 1][kk];
            float a2s = As[ty4 + 2][kk], a3s = As[ty4 + 3][kk];
            float b0s = Bs[tx4 + 0][kk], b1s = Bs[tx4 + 1][kk];
            float b2s = Bs[tx4 + 2][kk], b3s = Bs[tx4 + 3][kk];
            acc[0][0] += a0s*b0s; acc[0][1] += a0s*b1s; acc[0][2] += a0s*b2s; acc[0][3] += a0s*b3s;
            acc[1][0] += a1s*b0s; acc[1][1] += a1s*b1s; acc[1][2] += a1s*b2s; acc[1][3] += a1s*b3s;
            acc[2][0] += a2s*b0s; acc[2][1] += a2s*b1s; acc[2][2] += a2s*b2s; acc[2][3] += a2s*b3s;
            acc[3][0] += a3s*b0s; acc[3][1] += a3s*b1s; acc[3][2] += a3s*b2s; acc[3][3] += a3s*b3s;
        }
    }

#pragma unroll
    for (int iq = 0; iq < 4; iq++) {
        float4 v = make_float4(acc[iq][0], acc[iq][1], acc[iq][2], acc[iq][3]);
        *(float4*)(C + (size_t)(m0 + ty4 + iq) * OUTD + n0 + tx4) = v;
    }
}

// ---------------------------------------------------------------------------
extern "C" void kernel_launch(void* const* d_in, const int* in_sizes, int n_in,
                              void* d_out, int out_size, void* d_ws, size_t ws_size,
                              hipStream_t stream) {
    const float* x  = (const float*)d_in[0];
    const float* Wq = (const float*)d_in[1];
    const float* Wk = (const float*)d_in[2];
    const float* Wv = (const float*)d_in[3];
    const float* Wo = (const float*)d_in[4];
    float* out = (float*)d_out;

    // ws layout: [QKV fp32 SEQ x 1536] [Oh fp32 SEQ x 1024]  (~21 MB)
    float* QKV = (float*)d_ws;
    float* Oh  = QKV + (size_t)SEQ * NQKV;

    dim3 blk(256);
    gemm_qkv<<<dim3(SEQ / BM, NQKV / BN), blk, 0, stream>>>(x, Wq, Wk, Wv, QKV);
    attn_kernel<<<dim3(SEQ / QT, HQ), blk, 0, stream>>>(QKV, Oh);
    gemm_out<<<dim3(SEQ / BM, OUTD / BN), blk, 0, stream>>>(Oh, Wo, out);
}

// Round 4
// 467.924 us; speedup vs baseline: 3.1809x; 3.1809x over previous
//
#include <hip/hip_runtime.h>

// Problem constants
#define SEQ   2048
#define INF_  512          // IN dim
#define HQ    16           // query heads
#define KVH   4            // kv heads
#define DH    64           // head dim
#define NQ    (HQ*DH)      // 1024
#define NKV   (KVH*DH)     // 256
#define NQKV  (NQ + 2*NKV) // 1536
#define OUTD  512

typedef short v8s __attribute__((ext_vector_type(8)));   // 8 bf16 (4 VGPRs)
typedef float v4f __attribute__((ext_vector_type(4)));   // 4 fp32 acc

static __device__ __forceinline__ unsigned short f2bf(float f) {  // RNE
    union { float f; unsigned int i; } c; c.f = f;
    unsigned int lsb = (c.i >> 16) & 1u;
    c.i += 0x7fffu + lsb;
    return (unsigned short)(c.i >> 16);
}
static __device__ __forceinline__ unsigned short f2bfr(float f) { // round-half-up (hot path)
    union { float f; unsigned int i; } c; c.f = f;
    return (unsigned short)((c.i + 0x8000u) >> 16);
}

// ---------------------------------------------------------------------------
// GEMM 1: fused QKV projection, fp32 VALU, epilogue converts to bf16.
// QKVbf [SEQ][NQKV] bf16.  Tiles 64x64, BK=32, 256 threads, 4x4/thread.
// ---------------------------------------------------------------------------
#define BM 64
#define BN 64
#define BK 32

__global__ __launch_bounds__(256) void gemm_qkv(
    const float* __restrict__ x,
    const float* __restrict__ Wq,
    const float* __restrict__ Wk,
    const float* __restrict__ Wv,
    unsigned short* __restrict__ QKVbf)
{
    __shared__ float As[BM][BK + 1];
    __shared__ float Bs[BN][BK + 1];

    const int m0 = blockIdx.x * BM;
    const int n0 = blockIdx.y * BN;

    const float* Bp;
    int brow0;
    if (n0 < NQ)            { Bp = Wq; brow0 = n0; }
    else if (n0 < NQ + NKV) { Bp = Wk; brow0 = n0 - NQ; }
    else                    { Bp = Wv; brow0 = n0 - NQ - NKV; }

    const int tid = threadIdx.x;
    const int lr = tid >> 2;
    const int lc = (tid & 3) * 8;
    const int ty4 = (tid >> 4) * 4;
    const int tx4 = (tid & 15) * 4;

    float acc[4][4] = {};

    for (int kb = 0; kb < INF_; kb += BK) {
        const float* ap = x  + (size_t)(m0 + lr) * INF_ + kb + lc;
        const float* bp = Bp + (size_t)(brow0 + lr) * INF_ + kb + lc;
        float4 a0 = *(const float4*)(ap);
        float4 a1 = *(const float4*)(ap + 4);
        float4 b0 = *(const float4*)(bp);
        float4 b1 = *(const float4*)(bp + 4);
        __syncthreads();
        As[lr][lc]     = a0.x; As[lr][lc + 1] = a0.y;
        As[lr][lc + 2] = a0.z; As[lr][lc + 3] = a0.w;
        As[lr][lc + 4] = a1.x; As[lr][lc + 5] = a1.y;
        As[lr][lc + 6] = a1.z; As[lr][lc + 7] = a1.w;
        Bs[lr][lc]     = b0.x; Bs[lr][lc + 1] = b0.y;
        Bs[lr][lc + 2] = b0.z; Bs[lr][lc + 3] = b0.w;
        Bs[lr][lc + 4] = b1.x; Bs[lr][lc + 5] = b1.y;
        Bs[lr][lc + 6] = b1.z; Bs[lr][lc + 7] = b1.w;
        __syncthreads();
#pragma unroll
        for (int kk = 0; kk < BK; kk++) {
            float a0s = As[ty4 + 0][kk], a1s = As[ty4 + 1][kk];
            float a2s = As[ty4 + 2][kk], a3s = As[ty4 + 3][kk];
            float b0s = Bs[tx4 + 0][kk], b1s = Bs[tx4 + 1][kk];
            float b2s = Bs[tx4 + 2][kk], b3s = Bs[tx4 + 3][kk];
            acc[0][0] += a0s*b0s; acc[0][1] += a0s*b1s; acc[0][2] += a0s*b2s; acc[0][3] += a0s*b3s;
            acc[1][0] += a1s*b0s; acc[1][1] += a1s*b1s; acc[1][2] += a1s*b2s; acc[1][3] += a1s*b3s;
            acc[2][0] += a2s*b0s; acc[2][1] += a2s*b1s; acc[2][2] += a2s*b2s; acc[2][3] += a2s*b3s;
            acc[3][0] += a3s*b0s; acc[3][1] += a3s*b1s; acc[3][2] += a3s*b2s; acc[3][3] += a3s*b3s;
        }
    }

#pragma unroll
    for (int i = 0; i < 4; i++) {
        ushort4 v = make_ushort4(f2bf(acc[i][0]), f2bf(acc[i][1]),
                                 f2bf(acc[i][2]), f2bf(acc[i][3]));
        *(ushort4*)(QKVbf + (size_t)(m0 + ty4 + i) * NQKV + n0 + tx4) = v;
    }
}

// ---------------------------------------------------------------------------
// MFMA flash attention. Block = (64 q-rows, head h); 4 waves x 16 rows.
// KV tile = 64 cols; g-loop (4 kv heads) inside; online softmax per row.
// Fragment layouts (measured m89/m120):
//   A[m=lane&15][k=quad*8+j], B[k=quad*8+j][n=lane&15], C: col=lane&15,
//   row=quad*4+reg.  LDS strides 72 bf16 (36 dw = 4 mod 32 -> BW-floor b128).
// ---------------------------------------------------------------------------
__global__ __launch_bounds__(256, 2) void attn_mfma(
    const unsigned short* __restrict__ QKVbf, float* __restrict__ Oh)
{
    __shared__ unsigned short Qs [64][72];
    __shared__ unsigned short Ks [64][72];
    __shared__ unsigned short VsT[64][72];      // VsT[d][j]
    __shared__ unsigned short Ps [4][16][72];   // per-wave P round-trip

    const int qi  = (int)(gridDim.x - 1u - blockIdx.x);  // heavy tiles first
    const int h   = blockIdx.y;
    const int q0  = qi * 64;
    const int tid = threadIdx.x;
    const int w    = tid >> 6, lane = tid & 63;
    const int n    = lane & 15, quad = lane >> 4;
    const int r0   = w * 16;

    // stage Q (once): rows q0..q0+63, head h, bf16
    {
        const int r = tid >> 2, c = (tid & 3) * 16;
        const unsigned short* src = QKVbf + (size_t)(q0 + r) * NQKV + h * DH + c;
        uint4 v0 = *(const uint4*)(src);
        uint4 v1 = *(const uint4*)(src + 8);
        *(uint4*)&Qs[r][c]     = v0;
        *(uint4*)&Qs[r][c + 8] = v1;
    }
    __syncthreads();

    const v8s aq0 = *(const v8s*)&Qs[r0 + n][quad * 8];
    const v8s aq1 = *(const v8s*)&Qs[r0 + n][32 + quad * 8];

    v4f Ofin[4];
#pragma unroll
    for (int dt = 0; dt < 4; dt++) Ofin[dt] = (v4f){0.f, 0.f, 0.f, 0.f};

    const int ntile = qi + 1;

    for (int g = 0; g < KVH; g++) {
        float mst[4] = {-INFINITY, -INFINITY, -INFINITY, -INFINITY};
        float lst[4] = {0.f, 0.f, 0.f, 0.f};
        v4f Oacc[4];
#pragma unroll
        for (int dt = 0; dt < 4; dt++) Oacc[dt] = (v4f){0.f, 0.f, 0.f, 0.f};

        for (int tt = 0; tt < ntile; tt++) {
            const int t0 = tt * 64;
            __syncthreads();   // prior tile's MFMA reads of Ks/VsT done
            {   // stage K: Ks[j][d], coalesced loads
                const int j = tid >> 2, c = (tid & 3) * 16;
                const unsigned short* src =
                    QKVbf + (size_t)(t0 + j) * NQKV + NQ + g * DH + c;
                uint4 v0 = *(const uint4*)(src);
                uint4 v1 = *(const uint4*)(src + 8);
                *(uint4*)&Ks[j][c]     = v0;
                *(uint4*)&Ks[j][c + 8] = v1;
            }
            {   // stage V transposed: VsT[d][j] (b16 writes, 2-way = free)
                const int j = tid & 63, sec = tid >> 6;
                const unsigned short* src =
                    QKVbf + (size_t)(t0 + j) * NQKV + NQ + NKV + g * DH + sec * 16;
                uint4 v0 = *(const uint4*)(src);
                uint4 v1 = *(const uint4*)(src + 8);
                unsigned short tmp[16];
                *(uint4*)&tmp[0] = v0;
                *(uint4*)&tmp[8] = v1;
#pragma unroll
                for (int mm = 0; mm < 16; mm++) VsT[sec * 16 + mm][j] = tmp[mm];
            }
            __syncthreads();

            // scores: 16 rows x 64 cols, K-dim 64 (2 MFMAs per 16x16 tile)
            v4f sc[4];
#pragma unroll
            for (int ct = 0; ct < 4; ct++) {
                v8s b0 = *(const v8s*)&Ks[ct * 16 + n][quad * 8];
                v8s b1 = *(const v8s*)&Ks[ct * 16 + n][32 + quad * 8];
                v4f z = (v4f){0.f, 0.f, 0.f, 0.f};
                v4f t = __builtin_amdgcn_mfma_f32_16x16x32_bf16(aq0, b0, z, 0, 0, 0);
                sc[ct] = __builtin_amdgcn_mfma_f32_16x16x32_bf16(aq1, b1, t, 0, 0, 0);
            }

            // scale + causal mask
            const int rowg = q0 + r0 + quad * 4;
#pragma unroll
            for (int ct = 0; ct < 4; ct++) {
                const int col = t0 + ct * 16 + n;
#pragma unroll
                for (int reg = 0; reg < 4; reg++) {
                    float s = sc[ct][reg] * 0.125f;
                    sc[ct][reg] = (col <= rowg + reg) ? s : -INFINITY;
                }
            }

            // row max (across ct, then across the 16 lanes of the quad group)
            float mx[4], alpha[4], rs[4];
#pragma unroll
            for (int reg = 0; reg < 4; reg++) {
                float v = fmaxf(fmaxf(sc[0][reg], sc[1][reg]),
                                fmaxf(sc[2][reg], sc[3][reg]));
                v = fmaxf(v, __shfl_xor(v, 1));
                v = fmaxf(v, __shfl_xor(v, 2));
                v = fmaxf(v, __shfl_xor(v, 4));
                v = fmaxf(v, __shfl_xor(v, 8));
                mx[reg] = v;
            }
#pragma unroll
            for (int reg = 0; reg < 4; reg++) {
                float mn = fmaxf(mst[reg], mx[reg]);   // finite: col t0<=row in tile
                alpha[reg] = __expf(mst[reg] - mn);    // first tile: exp(-inf)=0
                mst[reg] = mn;
                rs[reg] = 0.f;
            }
#pragma unroll
            for (int ct = 0; ct < 4; ct++) {
#pragma unroll
                for (int reg = 0; reg < 4; reg++) {
                    float p = __expf(sc[ct][reg] - mst[reg]);  // masked -> 0
                    sc[ct][reg] = p;
                    rs[reg] += p;
                }
            }
            // P: C-layout -> LDS (A-layout readback), bf16
#pragma unroll
            for (int ct = 0; ct < 4; ct++) {
#pragma unroll
                for (int reg = 0; reg < 4; reg++)
                    Ps[w][quad * 4 + reg][ct * 16 + n] = f2bfr(sc[ct][reg]);
            }
            // l update + O rescale
#pragma unroll
            for (int reg = 0; reg < 4; reg++) {
                float v = rs[reg];
                v += __shfl_xor(v, 1);
                v += __shfl_xor(v, 2);
                v += __shfl_xor(v, 4);
                v += __shfl_xor(v, 8);
                lst[reg] = lst[reg] * alpha[reg] + v;
            }
#pragma unroll
            for (int dt = 0; dt < 4; dt++)
#pragma unroll
                for (int reg = 0; reg < 4; reg++)
                    Oacc[dt][reg] *= alpha[reg];

            // PV: P(16x64) x V(64x64); per-wave Ps -> no barrier needed
            v8s ap0 = *(const v8s*)&Ps[w][n][quad * 8];
            v8s ap1 = *(const v8s*)&Ps[w][n][32 + quad * 8];
#pragma unroll
            for (int dt = 0; dt < 4; dt++) {
                v8s bv0 = *(const v8s*)&VsT[dt * 16 + n][quad * 8];
                v8s bv1 = *(const v8s*)&VsT[dt * 16 + n][32 + quad * 8];
                Oacc[dt] = __builtin_amdgcn_mfma_f32_16x16x32_bf16(ap0, bv0, Oacc[dt], 0, 0, 0);
                Oacc[dt] = __builtin_amdgcn_mfma_f32_16x16x32_bf16(ap1, bv1, Oacc[dt], 0, 0, 0);
            }
        }

        // fold this kv head into the average
#pragma unroll
        for (int reg = 0; reg < 4; reg++) {
            float inv = 0.25f / lst[reg];
#pragma unroll
            for (int dt = 0; dt < 4; dt++)
                Ofin[dt][reg] += Oacc[dt][reg] * inv;
        }
    }

    // write Oh fp32 [S][NQ]
#pragma unroll
    for (int reg = 0; reg < 4; reg++) {
        float* dst = Oh + (size_t)(q0 + r0 + quad * 4 + reg) * NQ + h * DH + n;
#pragma unroll
        for (int dt = 0; dt < 4; dt++)
            dst[dt * 16] = Ofin[dt][reg];
    }
}

// ---------------------------------------------------------------------------
// GEMM 2: out[s][o] = sum_j Oh[s][j] * Wo[o][j].  All fp32.
// ---------------------------------------------------------------------------
__global__ __launch_bounds__(256) void gemm_out(
    const float* __restrict__ A,
    const float* __restrict__ Wo,
    float* __restrict__ C)
{
    __shared__ float As[BM][BK + 1];
    __shared__ float Bs[BN][BK + 1];

    const int m0 = blockIdx.x * BM;
    const int n0 = blockIdx.y * BN;
    const int tid = threadIdx.x;
    const int lr = tid >> 2;
    const int lc = (tid & 3) * 8;
    const int ty4 = (tid >> 4) * 4;
    const int tx4 = (tid & 15) * 4;

    float acc[4][4] = {};

    for (int kb = 0; kb < NQ; kb += BK) {
        const float* ap = A  + (size_t)(m0 + lr) * NQ + kb + lc;
        const float* bp = Wo + (size_t)(n0 + lr) * NQ + kb + lc;
        float4 a0 = *(const float4*)(ap);
        float4 a1 = *(const float4*)(ap + 4);
        float4 b0 = *(const float4*)(bp);
        float4 b1 = *(const float4*)(bp + 4);
        __syncthreads();
        As[lr][lc]     = a0.x; As[lr][lc + 1] = a0.y;
        As[lr][lc + 2] = a0.z; As[lr][lc + 3] = a0.w;
        As[lr][lc + 4] = a1.x; As[lr][lc + 5] = a1.y;
        As[lr][lc + 6] = a1.z; As[lr][lc + 7] = a1.w;
        Bs[lr][lc]     = b0.x; Bs[lr][lc + 1] = b0.y;
        Bs[lr][lc + 2] = b0.z; Bs[lr][lc + 3] = b0.w;
        Bs[lr][lc + 4] = b1.x; Bs[lr][lc + 5] = b1.y;
        Bs[lr][lc + 6] = b1.z; Bs[lr][lc + 7] = b1.w;
        __syncthreads();
#pragma unroll
        for (int kk = 0; kk < BK; kk++) {
            float a0s = As[ty4 + 0][kk], a1s = As[ty4 + 1][kk];
            float a2s = As[ty4 + 2][kk], a3s = As[ty4 + 3][kk];
            float b0s = Bs[tx4 + 0][kk], b1s = Bs[tx4 + 1][kk];
            float b2s = Bs[tx4 + 2][kk], b3s = Bs[tx4 + 3][kk];
            acc[0][0] += a0s*b0s; acc[0][1] += a0s*b1s; acc[0][2] += a0s*b2s; acc[0][3] += a0s*b3s;
            acc[1][0] += a1s*b0s; acc[1][1] += a1s*b1s; acc[1][2] += a1s*b2s; acc[1][3] += a1s*b3s;
            acc[2][0] += a2s*b0s; acc[2][1] += a2s*b1s; acc[2][2] += a2s*b2s; acc[2][3] += a2s*b3s;
            acc[3][0] += a3s*b0s; acc[3][1] += a3s*b1s; acc[3][2] += a3s*b2s; acc[3][3] += a3s*b3s;
        }
    }

#pragma unroll
    for (int iq = 0; iq < 4; iq++) {
        float4 v = make_float4(acc[iq][0], acc[iq][1], acc[iq][2], acc[iq][3]);
        *(float4*)(C + (size_t)(m0 + ty4 + iq) * OUTD + n0 + tx4) = v;
    }
}

// ---------------------------------------------------------------------------
extern "C" void kernel_launch(void* const* d_in, const int* in_sizes, int n_in,
                              void* d_out, int out_size, void* d_ws, size_t ws_size,
                              hipStream_t stream) {
    const float* x  = (const float*)d_in[0];
    const float* Wq = (const float*)d_in[1];
    const float* Wk = (const float*)d_in[2];
    const float* Wv = (const float*)d_in[3];
    const float* Wo = (const float*)d_in[4];
    float* out = (float*)d_out;

    // ws: QKVbf bf16 [SEQ][1536] (6.29 MB), then Oh fp32 [SEQ][1024] (8.39 MB)
    unsigned short* QKVbf = (unsigned short*)d_ws;
    float* Oh = (float*)((char*)d_ws + (size_t)SEQ * NQKV * sizeof(unsigned short));

    dim3 blk(256);
    gemm_qkv<<<dim3(SEQ / BM, NQKV / BN), blk, 0, stream>>>(x, Wq, Wk, Wv, QKVbf);
    attn_mfma<<<dim3(SEQ / 64, HQ), blk, 0, stream>>>(QKVbf, Oh);
    gemm_out<<<dim3(SEQ / BM, OUTD / BN), blk, 0, stream>>>(Oh, Wo, out);
}

// Round 5
// 224.421 us; speedup vs baseline: 6.6323x; 2.0850x over previous
//
#include <hip/hip_runtime.h>

// Problem constants
#define SEQ   2048
#define INF_  512          // IN dim
#define HQ    16           // query heads
#define KVH   4            // kv heads
#define DH    64           // head dim
#define NQ    (HQ*DH)      // 1024
#define NKV   (KVH*DH)     // 256
#define NQKV  (NQ + 2*NKV) // 1536
#define OUTD  512

typedef short v8s __attribute__((ext_vector_type(8)));   // 8 bf16 (4 VGPRs)
typedef float v4f __attribute__((ext_vector_type(4)));   // 4 fp32 acc

static __device__ __forceinline__ float bf2f(unsigned short u) {
    union { unsigned int i; float f; } c;
    c.i = ((unsigned int)u) << 16;
    return c.f;
}
static __device__ __forceinline__ unsigned short f2bf(float f) {  // RNE
    union { float f; unsigned int i; } c; c.f = f;
    unsigned int lsb = (c.i >> 16) & 1u;
    c.i += 0x7fffu + lsb;
    return (unsigned short)(c.i >> 16);
}
static __device__ __forceinline__ unsigned short f2bfr(float f) { // round-half-up (p>=0)
    union { float f; unsigned int i; } c; c.f = f;
    return (unsigned short)((c.i + 0x8000u) >> 16);
}

// ===========================================================================
// GEMM 1 (MFMA): QKV projection. C[s][n] = sum_k x[s][k]*W[n][k], fp32 in,
// bf16 out. 128x128 tile, kstep 32, 256 thr / 4 waves x (32 rows x 128 cols).
// Q part pre-scaled by 0.125 (exact). V part written TRANSPOSED to Vt[256][S].
// ===========================================================================
__global__ __launch_bounds__(256) void gemm_qkv(
    const float* __restrict__ x,
    const float* __restrict__ Wq,
    const float* __restrict__ Wk,
    const float* __restrict__ Wv,
    unsigned short* __restrict__ QKVbf,
    unsigned short* __restrict__ Vt)
{
    __shared__ unsigned short Asb[128][40];
    __shared__ unsigned short Bsb[128][40];

    const int m0 = blockIdx.x * 128;
    const int n0 = blockIdx.y * 128;

    const float* Bp; float scale; int role;   // 0=Q 1=K 2=V
    if (n0 < NQ)            { Bp = Wq + (size_t)n0 * INF_;          scale = 0.125f; role = 0; }
    else if (n0 < NQ + NKV) { Bp = Wk + (size_t)(n0 - NQ) * INF_;   scale = 1.f;    role = 1; }
    else                    { Bp = Wv + (size_t)(n0 - NQ - NKV) * INF_; scale = 1.f; role = 2; }

    const int tid = threadIdx.x;
    const int w = tid >> 6, lane = tid & 63;
    const int n = lane & 15, quad = lane >> 4;
    const int r0w = w * 32;
    const int sr = tid >> 1, sc0 = (tid & 1) * 16;  // staging: row, k-part

    v4f acc[2][8];
#pragma unroll
    for (int rt = 0; rt < 2; rt++)
#pragma unroll
        for (int ct = 0; ct < 8; ct++) acc[rt][ct] = (v4f){0.f,0.f,0.f,0.f};

    for (int kb = 0; kb < INF_; kb += 32) {
        const float* ap = x  + (size_t)(m0 + sr) * INF_ + kb + sc0;
        const float* bp = Bp + (size_t)sr * INF_ + kb + sc0;
        float4 a0 = *(const float4*)(ap),     a1 = *(const float4*)(ap + 4);
        float4 a2 = *(const float4*)(ap + 8), a3 = *(const float4*)(ap + 12);
        float4 b0 = *(const float4*)(bp),     b1 = *(const float4*)(bp + 4);
        float4 b2 = *(const float4*)(bp + 8), b3 = *(const float4*)(bp + 12);
        __syncthreads();
        {
            unsigned short ta[16], tb[16];
            const float* fa = (const float*)&a0;  // a0..a3 contiguous on stack? avoid: manual
            ta[0]=f2bf(a0.x); ta[1]=f2bf(a0.y); ta[2]=f2bf(a0.z); ta[3]=f2bf(a0.w);
            ta[4]=f2bf(a1.x); ta[5]=f2bf(a1.y); ta[6]=f2bf(a1.z); ta[7]=f2bf(a1.w);
            ta[8]=f2bf(a2.x); ta[9]=f2bf(a2.y); ta[10]=f2bf(a2.z); ta[11]=f2bf(a2.w);
            ta[12]=f2bf(a3.x); ta[13]=f2bf(a3.y); ta[14]=f2bf(a3.z); ta[15]=f2bf(a3.w);
            tb[0]=f2bf(b0.x); tb[1]=f2bf(b0.y); tb[2]=f2bf(b0.z); tb[3]=f2bf(b0.w);
            tb[4]=f2bf(b1.x); tb[5]=f2bf(b1.y); tb[6]=f2bf(b1.z); tb[7]=f2bf(b1.w);
            tb[8]=f2bf(b2.x); tb[9]=f2bf(b2.y); tb[10]=f2bf(b2.z); tb[11]=f2bf(b2.w);
            tb[12]=f2bf(b3.x); tb[13]=f2bf(b3.y); tb[14]=f2bf(b3.z); tb[15]=f2bf(b3.w);
            (void)fa;
            *(uint4*)&Asb[sr][sc0]     = *(uint4*)&ta[0];
            *(uint4*)&Asb[sr][sc0 + 8] = *(uint4*)&ta[8];
            *(uint4*)&Bsb[sr][sc0]     = *(uint4*)&tb[0];
            *(uint4*)&Bsb[sr][sc0 + 8] = *(uint4*)&tb[8];
        }
        __syncthreads();

        v8s af[2];
        af[0] = *(const v8s*)&Asb[r0w + n][quad * 8];
        af[1] = *(const v8s*)&Asb[r0w + 16 + n][quad * 8];
#pragma unroll
        for (int ct = 0; ct < 8; ct++) {
            v8s bf = *(const v8s*)&Bsb[ct * 16 + n][quad * 8];
            acc[0][ct] = __builtin_amdgcn_mfma_f32_16x16x32_bf16(af[0], bf, acc[0][ct], 0, 0, 0);
            acc[1][ct] = __builtin_amdgcn_mfma_f32_16x16x32_bf16(af[1], bf, acc[1][ct], 0, 0, 0);
        }
    }

    // epilogue: C row = m0+r0w+rt*16+quad*4+reg, col = n0+ct*16+n
#pragma unroll
    for (int rt = 0; rt < 2; rt++) {
#pragma unroll
        for (int ct = 0; ct < 8; ct++) {
#pragma unroll
            for (int reg = 0; reg < 4; reg++) {
                const int row = m0 + r0w + rt * 16 + quad * 4 + reg;
                const int col = n0 + ct * 16 + n;
                float v = acc[rt][ct][reg] * scale;
                if (role == 2) Vt[(size_t)(col - NQ - NKV) * SEQ + row] = f2bf(v);
                else           QKVbf[(size_t)row * NQKV + col] = f2bf(v);
            }
        }
    }
}

// ===========================================================================
// MFMA flash attention, max-free softmax (scores bounded ~|2|: exp safe).
// Block = 128 q-rows x head x g-pair; 4 waves x 32 rows. 512 blocks:
// bx & bx+256 identical work, bx & bx+128 complementary -> balanced.
// Double-buffered K/V staging with VGPR prefetch. Output: bf16 partial-O
// halves Oh0 (g0,1) / Oh1 (g2,3), summed later in gemm_out staging.
// ===========================================================================
__global__ __launch_bounds__(256, 2) void attn_mfma(
    const unsigned short* __restrict__ QKVbf,
    const unsigned short* __restrict__ Vt,
    unsigned short* __restrict__ Oh0,
    unsigned short* __restrict__ Oh1)
{
    __shared__ unsigned short Qs [128][72];
    __shared__ unsigned short Ks [2][64][72];
    __shared__ unsigned short VsT[2][64][72];   // VsT[d][j]
    __shared__ unsigned short Ps [4][32][72];   // per-wave P round-trip

    const int bx  = blockIdx.x;
    const int h   = bx & 15;
    const int j   = (bx >> 4) & 15;
    const int gp  = bx >> 8;                         // 0 or 1
    const int qi2 = (j < 8) ? (15 - j) : (j - 8);    // balanced pairing
    const int q0  = qi2 * 128;
    const int tid = threadIdx.x;
    const int w = tid >> 6, lane = tid & 63;
    const int n = lane & 15, quad = lane >> 4;
    const int r0 = w * 32;

    // stage Q (once): 128 rows x 64 d (already pre-scaled by 1/8)
    {
        const int r = tid >> 1, c = (tid & 1) * 32;
        const unsigned short* src = QKVbf + (size_t)(q0 + r) * NQKV + h * DH + c;
        uint4 v0 = *(const uint4*)(src);
        uint4 v1 = *(const uint4*)(src + 8);
        uint4 v2 = *(const uint4*)(src + 16);
        uint4 v3 = *(const uint4*)(src + 24);
        *(uint4*)&Qs[r][c]      = v0;
        *(uint4*)&Qs[r][c + 8]  = v1;
        *(uint4*)&Qs[r][c + 16] = v2;
        *(uint4*)&Qs[r][c + 24] = v3;
    }
    __syncthreads();

    v8s aq[2][2];
#pragma unroll
    for (int rt = 0; rt < 2; rt++) {
        aq[rt][0] = *(const v8s*)&Qs[r0 + rt * 16 + n][quad * 8];
        aq[rt][1] = *(const v8s*)&Qs[r0 + rt * 16 + n][32 + quad * 8];
    }

    v4f Ofin[2][4];
#pragma unroll
    for (int rt = 0; rt < 2; rt++)
#pragma unroll
        for (int dt = 0; dt < 4; dt++) Ofin[rt][dt] = (v4f){0.f,0.f,0.f,0.f};

    const int ntile = 2 * qi2 + 2;
    const int krow = tid >> 2, kc = (tid & 3) * 16;  // K staging map
    const int vd   = tid >> 2, vj = (tid & 3) * 16;  // V staging map

    for (int gg = 0; gg < 2; gg++) {
        const int g = gp * 2 + gg;
        float lst[2][4] = {{0.f,0.f,0.f,0.f},{0.f,0.f,0.f,0.f}};
        v4f Oacc[2][4];
#pragma unroll
        for (int rt = 0; rt < 2; rt++)
#pragma unroll
            for (int dt = 0; dt < 4; dt++) Oacc[rt][dt] = (v4f){0.f,0.f,0.f,0.f};

        const unsigned short* kbase = QKVbf + NQ + g * DH + kc;
        const unsigned short* vbase = Vt + (size_t)(g * DH + vd) * SEQ + vj;

        // preload tile 0
        uint4 kr0 = *(const uint4*)(kbase + (size_t)krow * NQKV);
        uint4 kr1 = *(const uint4*)(kbase + (size_t)krow * NQKV + 8);
        uint4 vr0 = *(const uint4*)(vbase);
        uint4 vr1 = *(const uint4*)(vbase + 8);

        for (int tt = 0; tt < ntile; tt++) {
            const int buf = tt & 1;
            const int t0 = tt * 64;
            *(uint4*)&Ks[buf][krow][kc]      = kr0;
            *(uint4*)&Ks[buf][krow][kc + 8]  = kr1;
            *(uint4*)&VsT[buf][vd][vj]       = vr0;
            *(uint4*)&VsT[buf][vd][vj + 8]   = vr1;
            if (tt + 1 < ntile) {
                const int t1 = (tt + 1) * 64;
                kr0 = *(const uint4*)(kbase + (size_t)(t1 + krow) * NQKV);
                kr1 = *(const uint4*)(kbase + (size_t)(t1 + krow) * NQKV + 8);
                vr0 = *(const uint4*)(vbase + t1);
                vr1 = *(const uint4*)(vbase + t1 + 8);
            }
            __syncthreads();

            const int rowbase0 = q0 + r0;         // rt=0 min row
            const int rowbase1 = q0 + r0 + 16;    // rt=1 min row
            const bool do0 = (t0 <= rowbase0 + 15);
            const bool do1 = (t0 <= rowbase1 + 15);
            if (do1) {
                // QK: shared B-frags across rt
                v4f sc[2][4];
                const v4f z = (v4f){0.f,0.f,0.f,0.f};
#pragma unroll
                for (int ct = 0; ct < 4; ct++) {
                    v8s b0 = *(const v8s*)&Ks[buf][ct * 16 + n][quad * 8];
                    v8s b1 = *(const v8s*)&Ks[buf][ct * 16 + n][32 + quad * 8];
                    if (do0) {
                        v4f t = __builtin_amdgcn_mfma_f32_16x16x32_bf16(aq[0][0], b0, z, 0, 0, 0);
                        sc[0][ct] = __builtin_amdgcn_mfma_f32_16x16x32_bf16(aq[0][1], b1, t, 0, 0, 0);
                    }
                    v4f t1 = __builtin_amdgcn_mfma_f32_16x16x32_bf16(aq[1][0], b0, z, 0, 0, 0);
                    sc[1][ct] = __builtin_amdgcn_mfma_f32_16x16x32_bf16(aq[1][1], b1, t1, 0, 0, 0);
                }
                // causal mask (diagonal tiles only), exp, l-accum, P write
#pragma unroll
                for (int rt = 0; rt < 2; rt++) {
                    if (rt == 0 && !do0) continue;
                    const int rowbase = (rt == 0) ? rowbase0 : rowbase1;
                    const int rowq = rowbase + quad * 4;
                    if (t0 + 63 > rowbase) {
#pragma unroll
                        for (int ct = 0; ct < 4; ct++) {
                            const int col = t0 + ct * 16 + n;
#pragma unroll
                            for (int reg = 0; reg < 4; reg++)
                                sc[rt][ct][reg] = (col <= rowq + reg) ? sc[rt][ct][reg] : -INFINITY;
                        }
                    }
#pragma unroll
                    for (int ct = 0; ct < 4; ct++) {
#pragma unroll
                        for (int reg = 0; reg < 4; reg++) {
                            float p = __expf(sc[rt][ct][reg]);   // max-free: |s|<~2
                            lst[rt][reg] += p;
                            Ps[w][rt * 16 + quad * 4 + reg][ct * 16 + n] = f2bfr(p);
                        }
                    }
                }
                // PV: shared V B-frags across rt; per-wave Ps, no barrier
                v8s ap[2][2];
                if (do0) {
                    ap[0][0] = *(const v8s*)&Ps[w][n][quad * 8];
                    ap[0][1] = *(const v8s*)&Ps[w][n][32 + quad * 8];
                }
                ap[1][0] = *(const v8s*)&Ps[w][16 + n][quad * 8];
                ap[1][1] = *(const v8s*)&Ps[w][16 + n][32 + quad * 8];
#pragma unroll
                for (int dt = 0; dt < 4; dt++) {
                    v8s bv0 = *(const v8s*)&VsT[buf][dt * 16 + n][quad * 8];
                    v8s bv1 = *(const v8s*)&VsT[buf][dt * 16 + n][32 + quad * 8];
                    if (do0) {
                        Oacc[0][dt] = __builtin_amdgcn_mfma_f32_16x16x32_bf16(ap[0][0], bv0, Oacc[0][dt], 0, 0, 0);
                        Oacc[0][dt] = __builtin_amdgcn_mfma_f32_16x16x32_bf16(ap[0][1], bv1, Oacc[0][dt], 0, 0, 0);
                    }
                    Oacc[1][dt] = __builtin_amdgcn_mfma_f32_16x16x32_bf16(ap[1][0], bv0, Oacc[1][dt], 0, 0, 0);
                    Oacc[1][dt] = __builtin_amdgcn_mfma_f32_16x16x32_bf16(ap[1][1], bv1, Oacc[1][dt], 0, 0, 0);
                }
            }
        }

        // reduce l over the 16 lanes of each quad-group, fold into Ofin
#pragma unroll
        for (int rt = 0; rt < 2; rt++) {
#pragma unroll
            for (int reg = 0; reg < 4; reg++) {
                float L = lst[rt][reg];
                L += __shfl_xor(L, 1);
                L += __shfl_xor(L, 2);
                L += __shfl_xor(L, 4);
                L += __shfl_xor(L, 8);
                const float inv = 0.25f / L;   // col 0 always unmasked -> L>0
#pragma unroll
                for (int dt = 0; dt < 4; dt++)
                    Ofin[rt][dt][reg] += Oacc[rt][dt][reg] * inv;
            }
        }
    }

    // write partial-O half (bf16)
    unsigned short* Ohp = gp ? Oh1 : Oh0;
#pragma unroll
    for (int rt = 0; rt < 2; rt++) {
#pragma unroll
        for (int reg = 0; reg < 4; reg++) {
            const int row = q0 + r0 + rt * 16 + quad * 4 + reg;
            unsigned short* dst = Ohp + (size_t)row * NQ + h * DH + n;
#pragma unroll
            for (int dt = 0; dt < 4; dt++)
                dst[dt * 16] = f2bf(Ofin[rt][dt][reg]);
        }
    }
}

// ===========================================================================
// GEMM 2 (MFMA): out[s][o] = sum_j (Oh0+Oh1)[s][j] * Wo[o][j]. fp32 out.
// 64x64 tile, kstep 32, 256 blocks.
// ===========================================================================
__global__ __launch_bounds__(256) void gemm_out(
    const unsigned short* __restrict__ Oh0,
    const unsigned short* __restrict__ Oh1,
    const float* __restrict__ Wo,
    float* __restrict__ C)
{
    __shared__ unsigned short Asb[64][40];
    __shared__ unsigned short Bsb[64][40];

    const int m0 = blockIdx.x * 64;
    const int n0 = blockIdx.y * 64;
    const int tid = threadIdx.x;
    const int w = tid >> 6, lane = tid & 63;
    const int n = lane & 15, quad = lane >> 4;
    const int r0w = w * 16;
    const int sr = tid >> 2, sc8 = (tid & 3) * 8;

    v4f acc[4];
#pragma unroll
    for (int ct = 0; ct < 4; ct++) acc[ct] = (v4f){0.f,0.f,0.f,0.f};

    for (int kb = 0; kb < NQ; kb += 32) {
        const size_t aidx = (size_t)(m0 + sr) * NQ + kb + sc8;
        uint4 ua = *(const uint4*)(Oh0 + aidx);
        uint4 ub = *(const uint4*)(Oh1 + aidx);
        const float* bp = Wo + (size_t)(n0 + sr) * NQ + kb + sc8;
        float4 b0 = *(const float4*)(bp);
        float4 b1 = *(const float4*)(bp + 4);
        __syncthreads();
        {
            unsigned short ta[8], tb[8];
            unsigned int au[4] = {ua.x, ua.y, ua.z, ua.w};
            unsigned int bu[4] = {ub.x, ub.y, ub.z, ub.w};
#pragma unroll
            for (int q = 0; q < 4; q++) {
                float lo = bf2f((unsigned short)(au[q] & 0xffffu)) +
                           bf2f((unsigned short)(bu[q] & 0xffffu));
                float hi = bf2f((unsigned short)(au[q] >> 16)) +
                           bf2f((unsigned short)(bu[q] >> 16));
                ta[2*q]   = f2bf(lo);
                ta[2*q+1] = f2bf(hi);
            }
            tb[0]=f2bf(b0.x); tb[1]=f2bf(b0.y); tb[2]=f2bf(b0.z); tb[3]=f2bf(b0.w);
            tb[4]=f2bf(b1.x); tb[5]=f2bf(b1.y); tb[6]=f2bf(b1.z); tb[7]=f2bf(b1.w);
            *(uint4*)&Asb[sr][sc8] = *(uint4*)&ta[0];
            *(uint4*)&Bsb[sr][sc8] = *(uint4*)&tb[0];
        }
        __syncthreads();

        v8s af = *(const v8s*)&Asb[r0w + n][quad * 8];
#pragma unroll
        for (int ct = 0; ct < 4; ct++) {
            v8s bf = *(const v8s*)&Bsb[ct * 16 + n][quad * 8];
            acc[ct] = __builtin_amdgcn_mfma_f32_16x16x32_bf16(af, bf, acc[ct], 0, 0, 0);
        }
    }

#pragma unroll
    for (int ct = 0; ct < 4; ct++) {
#pragma unroll
        for (int reg = 0; reg < 4; reg++) {
            const int row = m0 + r0w + quad * 4 + reg;
            C[(size_t)row * OUTD + n0 + ct * 16 + n] = acc[ct][reg];
        }
    }
}

// ===========================================================================
extern "C" void kernel_launch(void* const* d_in, const int* in_sizes, int n_in,
                              void* d_out, int out_size, void* d_ws, size_t ws_size,
                              hipStream_t stream) {
    const float* x  = (const float*)d_in[0];
    const float* Wq = (const float*)d_in[1];
    const float* Wk = (const float*)d_in[2];
    const float* Wv = (const float*)d_in[3];
    const float* Wo = (const float*)d_in[4];
    float* out = (float*)d_out;

    // ws layout (bytes): QKVbf bf16 [2048][1536] @0 (6.29MB);
    // Vt bf16 [256][2048] @6291456 (1.05MB); Oh0/Oh1 bf16 [2048][1024]
    char* base = (char*)d_ws;
    unsigned short* QKVbf = (unsigned short*)(base);
    unsigned short* Vt    = (unsigned short*)(base + 6291456);
    unsigned short* Oh0   = (unsigned short*)(base + 7340032);
    unsigned short* Oh1   = (unsigned short*)(base + 11534336);

    dim3 blk(256);
    gemm_qkv<<<dim3(SEQ / 128, NQKV / 128), blk, 0, stream>>>(x, Wq, Wk, Wv, QKVbf, Vt);
    attn_mfma<<<dim3(512), blk, 0, stream>>>(QKVbf, Vt, Oh0, Oh1);
    gemm_out<<<dim3(SEQ / 64, OUTD / 64), blk, 0, stream>>>(Oh0, Oh1, Wo, out);
}

// Round 6
// 207.520 us; speedup vs baseline: 7.1725x; 1.0814x over previous
//
#include <hip/hip_runtime.h>
#include <hip/hip_bf16.h>

// Problem constants
#define SEQ   2048
#define INF_  512          // IN dim
#define HQ    16           // query heads
#define KVH   4            // kv heads
#define DH    64           // head dim
#define NQ    (HQ*DH)      // 1024
#define NKV   (KVH*DH)     // 256
#define NQKV  (NQ + 2*NKV) // 1536
#define OUTD  512

typedef short v8s __attribute__((ext_vector_type(8)));   // 8 bf16 (4 VGPRs)
typedef float v4f __attribute__((ext_vector_type(4)));   // 4 fp32 acc

static __device__ __forceinline__ float bf2f(unsigned short u) {
    union { unsigned int i; float f; } c;
    c.i = ((unsigned int)u) << 16;
    return c.f;
}
static __device__ __forceinline__ unsigned short f2bf(float f) {  // RNE
    union { float f; unsigned int i; } c; c.f = f;
    unsigned int lsb = (c.i >> 16) & 1u;
    c.i += 0x7fffu + lsb;
    return (unsigned short)(c.i >> 16);
}
static __device__ __forceinline__ unsigned int f2bf2(float lo, float hi) { // packed cvt
    union { __hip_bfloat162 h; unsigned int u; } c;
    c.h = __float22bfloat162_rn(make_float2(lo, hi));
    return c.u;
}
static __device__ __forceinline__ unsigned int addbf2(unsigned int a, unsigned int b) {
    float lo = bf2f((unsigned short)(a & 0xffffu)) + bf2f((unsigned short)(b & 0xffffu));
    float hi = bf2f((unsigned short)(a >> 16))     + bf2f((unsigned short)(b >> 16));
    return f2bf2(lo, hi);
}

// ===========================================================================
// GEMM 1 (MFMA): QKV projection, fp32 in -> bf16 out, packed cvt staging.
// 64 rows x 128 cols per block, kstep 32; grid 32x12 = 384 blocks.
// Q pre-scaled by 0.125 (exact). V written transposed to Vt[256][SEQ].
// ===========================================================================
__global__ __launch_bounds__(256) void gemm_qkv(
    const float* __restrict__ x,
    const float* __restrict__ Wq,
    const float* __restrict__ Wk,
    const float* __restrict__ Wv,
    unsigned short* __restrict__ QKVbf,
    unsigned short* __restrict__ Vt)
{
    __shared__ unsigned short Asb[64][40];
    __shared__ unsigned short Bsb[128][40];

    const int m0 = blockIdx.x * 64;
    const int n0 = blockIdx.y * 128;

    const float* Bp; float scale; int role;   // 0=Q 1=K 2=V
    if (n0 < NQ)            { Bp = Wq + (size_t)n0 * INF_;              scale = 0.125f; role = 0; }
    else if (n0 < NQ + NKV) { Bp = Wk + (size_t)(n0 - NQ) * INF_;       scale = 1.f;    role = 1; }
    else                    { Bp = Wv + (size_t)(n0 - NQ - NKV) * INF_; scale = 1.f;    role = 2; }

    const int tid = threadIdx.x;
    const int w = tid >> 6, lane = tid & 63;
    const int n = lane & 15, quad = lane >> 4;
    const int r0w = w * 16;
    const int ar = tid >> 2, ak = (tid & 3) * 8;
    const int br = tid >> 1, bk = (tid & 1) * 16;

    v4f acc[8];
#pragma unroll
    for (int ct = 0; ct < 8; ct++) acc[ct] = (v4f){0.f,0.f,0.f,0.f};

    for (int kb = 0; kb < INF_; kb += 32) {
        const float* ap = x  + (size_t)(m0 + ar) * INF_ + kb + ak;
        const float* bp = Bp + (size_t)br * INF_ + kb + bk;
        float4 a0 = *(const float4*)(ap),     a1 = *(const float4*)(ap + 4);
        float4 b0 = *(const float4*)(bp),     b1 = *(const float4*)(bp + 4);
        float4 b2 = *(const float4*)(bp + 8), b3 = *(const float4*)(bp + 12);
        __syncthreads();
        *(uint4*)&Asb[ar][ak] = make_uint4(f2bf2(a0.x,a0.y), f2bf2(a0.z,a0.w),
                                           f2bf2(a1.x,a1.y), f2bf2(a1.z,a1.w));
        *(uint4*)&Bsb[br][bk]     = make_uint4(f2bf2(b0.x,b0.y), f2bf2(b0.z,b0.w),
                                               f2bf2(b1.x,b1.y), f2bf2(b1.z,b1.w));
        *(uint4*)&Bsb[br][bk + 8] = make_uint4(f2bf2(b2.x,b2.y), f2bf2(b2.z,b2.w),
                                               f2bf2(b3.x,b3.y), f2bf2(b3.z,b3.w));
        __syncthreads();
        v8s af = *(const v8s*)&Asb[r0w + n][quad * 8];
#pragma unroll
        for (int ct = 0; ct < 8; ct++) {
            v8s bfb = *(const v8s*)&Bsb[ct * 16 + n][quad * 8];
            acc[ct] = __builtin_amdgcn_mfma_f32_16x16x32_bf16(af, bfb, acc[ct], 0, 0, 0);
        }
    }

    if (role == 2) {
        // Vt[d][s]: 4 consecutive s per lane -> b64 stores
#pragma unroll
        for (int ct = 0; ct < 8; ct++) {
            const int vcol = n0 - NQ - NKV + ct * 16 + n;
            uint2 pk = make_uint2(f2bf2(acc[ct][0], acc[ct][1]),
                                  f2bf2(acc[ct][2], acc[ct][3]));
            *(uint2*)(Vt + (size_t)vcol * SEQ + m0 + r0w + quad * 4) = pk;
        }
    } else {
#pragma unroll
        for (int ct = 0; ct < 8; ct++) {
#pragma unroll
            for (int reg = 0; reg < 4; reg++) {
                const int row = m0 + r0w + quad * 4 + reg;
                QKVbf[(size_t)row * NQKV + n0 + ct * 16 + n] = f2bf(acc[ct][reg] * scale);
            }
        }
    }
}

// ===========================================================================
// MFMA flash attention, S^T formulation (K·Q^T), max-free softmax.
// Block = 128 q-rows x head x g-pair; 4 waves x 32 rows (2 q-subtiles).
// C-layout of S^T: lane holds fixed q (=lane&15), 4 consecutive j
// (quad*4+reg) -> P^T writes are contiguous b64, PV = V^T·P^T reads P^T as
// a plain B-fragment (b128).  l is a per-lane scalar per q-subtile.
// ===========================================================================
__global__ __launch_bounds__(256, 2) void attn_mfma(
    const unsigned short* __restrict__ QKVbf,
    const unsigned short* __restrict__ Vt,
    unsigned short* __restrict__ Oh0,
    unsigned short* __restrict__ Oh1)
{
    __shared__ unsigned short Qs [128][72];
    __shared__ unsigned short Ks [2][64][72];
    __shared__ unsigned short VsT[2][64][72];   // VsT[d][j]
    __shared__ unsigned short PsT[4][32][72];   // per-wave P[q][j]

    const int bx  = blockIdx.x;
    const int h   = bx & 15;
    const int jb  = (bx >> 4) & 15;
    const int gp  = bx >> 8;                          // 0 or 1
    const int qi2 = (jb < 8) ? (15 - jb) : (jb - 8);  // balanced pairing
    const int q0  = qi2 * 128;
    const int tid = threadIdx.x;
    const int w = tid >> 6, lane = tid & 63;
    const int n = lane & 15, quad = lane >> 4;
    const int r0 = w * 32;

    // stage Q (once): 128 rows x 64 d (pre-scaled by 1/8)
    {
        const int r = tid >> 1, c = (tid & 1) * 32;
        const unsigned short* src = QKVbf + (size_t)(q0 + r) * NQKV + h * DH + c;
        uint4 v0 = *(const uint4*)(src);
        uint4 v1 = *(const uint4*)(src + 8);
        uint4 v2 = *(const uint4*)(src + 16);
        uint4 v3 = *(const uint4*)(src + 24);
        *(uint4*)&Qs[r][c]      = v0;
        *(uint4*)&Qs[r][c + 8]  = v1;
        *(uint4*)&Qs[r][c + 16] = v2;
        *(uint4*)&Qs[r][c + 24] = v3;
    }
    __syncthreads();

    // Q B-fragments (loop-invariant): B[k=d][n=q] == same bytes as row-major read
    v8s qf[2][2];
#pragma unroll
    for (int qt = 0; qt < 2; qt++) {
        qf[qt][0] = *(const v8s*)&Qs[r0 + qt * 16 + n][quad * 8];
        qf[qt][1] = *(const v8s*)&Qs[r0 + qt * 16 + n][32 + quad * 8];
    }

    v4f Ofin[2][4];
#pragma unroll
    for (int qt = 0; qt < 2; qt++)
#pragma unroll
        for (int dt = 0; dt < 4; dt++) Ofin[qt][dt] = (v4f){0.f,0.f,0.f,0.f};

    const int ntile = 2 * qi2 + 2;
    const int krow = tid >> 2, kc = (tid & 3) * 16;
    const int vd   = tid >> 2, vj = (tid & 3) * 16;
    const v4f z = (v4f){0.f,0.f,0.f,0.f};

    for (int gg = 0; gg < 2; gg++) {
        const int g = gp * 2 + gg;
        float lst[2] = {0.f, 0.f};
        v4f Oacc[2][4];
#pragma unroll
        for (int qt = 0; qt < 2; qt++)
#pragma unroll
            for (int dt = 0; dt < 4; dt++) Oacc[qt][dt] = (v4f){0.f,0.f,0.f,0.f};

        const unsigned short* kbase = QKVbf + NQ + g * DH + kc;
        const unsigned short* vbase = Vt + (size_t)(g * DH + vd) * SEQ + vj;

        uint4 kr0 = *(const uint4*)(kbase + (size_t)krow * NQKV);
        uint4 kr1 = *(const uint4*)(kbase + (size_t)krow * NQKV + 8);
        uint4 vr0 = *(const uint4*)(vbase);
        uint4 vr1 = *(const uint4*)(vbase + 8);

        for (int tt = 0; tt < ntile; tt++) {
            const int buf = tt & 1;
            const int t0 = tt * 64;
            *(uint4*)&Ks[buf][krow][kc]     = kr0;
            *(uint4*)&Ks[buf][krow][kc + 8] = kr1;
            *(uint4*)&VsT[buf][vd][vj]      = vr0;
            *(uint4*)&VsT[buf][vd][vj + 8]  = vr1;
            if (tt + 1 < ntile) {
                const int t1 = (tt + 1) * 64;
                kr0 = *(const uint4*)(kbase + (size_t)(t1 + krow) * NQKV);
                kr1 = *(const uint4*)(kbase + (size_t)(t1 + krow) * NQKV + 8);
                vr0 = *(const uint4*)(vbase + t1);
                vr1 = *(const uint4*)(vbase + t1 + 8);
            }
            __syncthreads();

            const bool do0 = (t0 <= q0 + r0 + 15);
            const bool do1 = (t0 <= q0 + r0 + 31);
            if (do1) {
                // S^T = K·Q^T : A = K-frag (rows j), B = Q-frag (cols q)
                v4f sc[2][4];
#pragma unroll
                for (int jt = 0; jt < 4; jt++) {
                    v8s kf0 = *(const v8s*)&Ks[buf][jt * 16 + n][quad * 8];
                    v8s kf1 = *(const v8s*)&Ks[buf][jt * 16 + n][32 + quad * 8];
                    if (do0) {
                        v4f t = __builtin_amdgcn_mfma_f32_16x16x32_bf16(kf0, qf[0][0], z, 0, 0, 0);
                        sc[0][jt] = __builtin_amdgcn_mfma_f32_16x16x32_bf16(kf1, qf[0][1], t, 0, 0, 0);
                    }
                    v4f t1 = __builtin_amdgcn_mfma_f32_16x16x32_bf16(kf0, qf[1][0], z, 0, 0, 0);
                    sc[1][jt] = __builtin_amdgcn_mfma_f32_16x16x32_bf16(kf1, qf[1][1], t1, 0, 0, 0);
                }

                // mask (diagonal region only) + exp + per-lane l + P^T b64 write
#pragma unroll
                for (int qt = 0; qt < 2; qt++) {
                    if (qt == 0 && !do0) continue;
                    const int qg = q0 + r0 + qt * 16 + n;   // this lane's q
                    if (t0 + 63 > q0 + r0 + qt * 16) {
#pragma unroll
                        for (int jt = 0; jt < 4; jt++) {
                            const int jg = t0 + jt * 16 + quad * 4;
#pragma unroll
                            for (int reg = 0; reg < 4; reg++)
                                sc[qt][jt][reg] = (jg + reg <= qg) ? sc[qt][jt][reg] : -INFINITY;
                        }
                    }
#pragma unroll
                    for (int jt = 0; jt < 4; jt++) {
                        float p0 = __expf(sc[qt][jt][0]);
                        float p1 = __expf(sc[qt][jt][1]);
                        float p2 = __expf(sc[qt][jt][2]);
                        float p3 = __expf(sc[qt][jt][3]);
                        lst[qt] += (p0 + p1) + (p2 + p3);
                        *(uint2*)&PsT[w][qt * 16 + n][jt * 16 + quad * 4] =
                            make_uint2(f2bf2(p0, p1), f2bf2(p2, p3));
                    }
                }

                // PV: O^T = V^T · P^T  (A = V^T frag, B = P^T frag; per-wave PsT)
                v8s pf[2][2];
                if (do0) {
                    pf[0][0] = *(const v8s*)&PsT[w][n][quad * 8];
                    pf[0][1] = *(const v8s*)&PsT[w][n][32 + quad * 8];
                }
                pf[1][0] = *(const v8s*)&PsT[w][16 + n][quad * 8];
                pf[1][1] = *(const v8s*)&PsT[w][16 + n][32 + quad * 8];
#pragma unroll
                for (int dt = 0; dt < 4; dt++) {
                    v8s vf0 = *(const v8s*)&VsT[buf][dt * 16 + n][quad * 8];
                    v8s vf1 = *(const v8s*)&VsT[buf][dt * 16 + n][32 + quad * 8];
                    if (do0) {
                        Oacc[0][dt] = __builtin_amdgcn_mfma_f32_16x16x32_bf16(vf0, pf[0][0], Oacc[0][dt], 0, 0, 0);
                        Oacc[0][dt] = __builtin_amdgcn_mfma_f32_16x16x32_bf16(vf1, pf[0][1], Oacc[0][dt], 0, 0, 0);
                    }
                    Oacc[1][dt] = __builtin_amdgcn_mfma_f32_16x16x32_bf16(vf0, pf[1][0], Oacc[1][dt], 0, 0, 0);
                    Oacc[1][dt] = __builtin_amdgcn_mfma_f32_16x16x32_bf16(vf1, pf[1][1], Oacc[1][dt], 0, 0, 0);
                }
            }
        }

        // fold g into average: l lives per-lane; reduce across the 4 quads
#pragma unroll
        for (int qt = 0; qt < 2; qt++) {
            float L = lst[qt];
            L += __shfl_xor(L, 16);
            L += __shfl_xor(L, 32);
            const float inv = 0.25f / L;   // j=0 always unmasked -> L>0
#pragma unroll
            for (int dt = 0; dt < 4; dt++)
#pragma unroll
                for (int reg = 0; reg < 4; reg++)
                    Ofin[qt][dt][reg] += Oacc[qt][dt][reg] * inv;
        }
    }

    // store O (bf16): O^T C-layout -> 4 consecutive d per (qt,dt) -> b64
    unsigned short* Ohp = gp ? Oh1 : Oh0;
#pragma unroll
    for (int qt = 0; qt < 2; qt++) {
        const int row = q0 + r0 + qt * 16 + n;
        unsigned short* dst = Ohp + (size_t)row * NQ + h * DH + quad * 4;
#pragma unroll
        for (int dt = 0; dt < 4; dt++) {
            uint2 pk = make_uint2(f2bf2(Ofin[qt][dt][0], Ofin[qt][dt][1]),
                                  f2bf2(Ofin[qt][dt][2], Ofin[qt][dt][3]));
            *(uint2*)(dst + dt * 16) = pk;
        }
    }
}

// ===========================================================================
// GEMM 2 (MFMA): out[s][o] = sum_j (Oh0+Oh1)[s][j] * Wo[o][j]. fp32 out.
// 64x64 tiles, kstep 32, grid 32x8 = 256 blocks.
// ===========================================================================
__global__ __launch_bounds__(256) void gemm_out(
    const unsigned short* __restrict__ Oh0,
    const unsigned short* __restrict__ Oh1,
    const float* __restrict__ Wo,
    float* __restrict__ C)
{
    __shared__ unsigned short Asb[64][40];
    __shared__ unsigned short Bsb[64][40];

    const int m0 = blockIdx.x * 64;
    const int n0 = blockIdx.y * 64;
    const int tid = threadIdx.x;
    const int w = tid >> 6, lane = tid & 63;
    const int n = lane & 15, quad = lane >> 4;
    const int r0w = w * 16;
    const int ar = tid >> 2, ak = (tid & 3) * 8;

    v4f acc[4];
#pragma unroll
    for (int ct = 0; ct < 4; ct++) acc[ct] = (v4f){0.f,0.f,0.f,0.f};

    for (int kb = 0; kb < NQ; kb += 32) {
        const size_t aidx = (size_t)(m0 + ar) * NQ + kb + ak;
        uint4 ua = *(const uint4*)(Oh0 + aidx);
        uint4 ub = *(const uint4*)(Oh1 + aidx);
        const float* bp = Wo + (size_t)(n0 + ar) * NQ + kb + ak;
        float4 b0 = *(const float4*)(bp);
        float4 b1 = *(const float4*)(bp + 4);
        __syncthreads();
        *(uint4*)&Asb[ar][ak] = make_uint4(addbf2(ua.x, ub.x), addbf2(ua.y, ub.y),
                                           addbf2(ua.z, ub.z), addbf2(ua.w, ub.w));
        *(uint4*)&Bsb[ar][ak] = make_uint4(f2bf2(b0.x,b0.y), f2bf2(b0.z,b0.w),
                                           f2bf2(b1.x,b1.y), f2bf2(b1.z,b1.w));
        __syncthreads();
        v8s af = *(const v8s*)&Asb[r0w + n][quad * 8];
#pragma unroll
        for (int ct = 0; ct < 4; ct++) {
            v8s bfb = *(const v8s*)&Bsb[ct * 16 + n][quad * 8];
            acc[ct] = __builtin_amdgcn_mfma_f32_16x16x32_bf16(af, bfb, acc[ct], 0, 0, 0);
        }
    }

#pragma unroll
    for (int ct = 0; ct < 4; ct++) {
#pragma unroll
        for (int reg = 0; reg < 4; reg++) {
            const int row = m0 + r0w + quad * 4 + reg;
            C[(size_t)row * OUTD + n0 + ct * 16 + n] = acc[ct][reg];
        }
    }
}

// ===========================================================================
extern "C" void kernel_launch(void* const* d_in, const int* in_sizes, int n_in,
                              void* d_out, int out_size, void* d_ws, size_t ws_size,
                              hipStream_t stream) {
    const float* x  = (const float*)d_in[0];
    const float* Wq = (const float*)d_in[1];
    const float* Wk = (const float*)d_in[2];
    const float* Wv = (const float*)d_in[3];
    const float* Wo = (const float*)d_in[4];
    float* out = (float*)d_out;

    // ws: QKVbf bf16 [2048][1536] @0; Vt bf16 [256][2048] @6291456;
    //     Oh0/Oh1 bf16 [2048][1024] @7340032 / @11534336
    char* base = (char*)d_ws;
    unsigned short* QKVbf = (unsigned short*)(base);
    unsigned short* Vt    = (unsigned short*)(base + 6291456);
    unsigned short* Oh0   = (unsigned short*)(base + 7340032);
    unsigned short* Oh1   = (unsigned short*)(base + 11534336);

    dim3 blk(256);
    gemm_qkv<<<dim3(SEQ / 64, NQKV / 128), blk, 0, stream>>>(x, Wq, Wk, Wv, QKVbf, Vt);
    attn_mfma<<<dim3(512), blk, 0, stream>>>(QKVbf, Vt, Oh0, Oh1);
    gemm_out<<<dim3(SEQ / 64, OUTD / 64), blk, 0, stream>>>(Oh0, Oh1, Wo, out);
}

// Round 8
// 167.763 us; speedup vs baseline: 8.8723x; 1.2370x over previous
//
#include <hip/hip_runtime.h>
#include <hip/hip_bf16.h>

// Problem constants
#define SEQ   2048
#define INF_  512          // IN dim
#define HQ    16           // query heads
#define KVH   4            // kv heads
#define DH    64           // head dim
#define NQ    (HQ*DH)      // 1024
#define NKV   (KVH*DH)     // 256
#define NQKV  (NQ + 2*NKV) // 1536
#define OUTD  512

typedef short v8s __attribute__((ext_vector_type(8)));   // 8 bf16 (4 VGPRs)
typedef float v4f __attribute__((ext_vector_type(4)));   // 4 fp32 acc

static __device__ __forceinline__ float bf2f(unsigned short u) {
    union { unsigned int i; float f; } c;
    c.i = ((unsigned int)u) << 16;
    return c.f;
}
static __device__ __forceinline__ unsigned short f2bf(float f) {  // RNE
    union { float f; unsigned int i; } c; c.f = f;
    unsigned int lsb = (c.i >> 16) & 1u;
    c.i += 0x7fffu + lsb;
    return (unsigned short)(c.i >> 16);
}
static __device__ __forceinline__ unsigned int f2bf2(float lo, float hi) { // packed cvt
    union { __hip_bfloat162 h; unsigned int u; } c;
    c.h = __float22bfloat162_rn(make_float2(lo, hi));
    return c.u;
}
static __device__ __forceinline__ unsigned int addbf2(unsigned int a, unsigned int b) {
    float lo = bf2f((unsigned short)(a & 0xffffu)) + bf2f((unsigned short)(b & 0xffffu));
    float hi = bf2f((unsigned short)(a >> 16))     + bf2f((unsigned short)(b >> 16));
    return f2bf2(lo, hi);
}

// ===========================================================================
// GEMM 1 (MFMA): QKV projection, fp32 in -> bf16 out.
// 64x64 tile, BK=64 (8 iters), register prefetch overlapping MFMA.
// Staging map: sr=tid>>2 (0..63), skc=(tid&3)*16 -> 16 floats/thread. Grid
// 32x24 = 768 blocks. Q pre-scaled by 0.125 (exact). V transposed to Vt.
// ===========================================================================
__global__ __launch_bounds__(256, 4) void gemm_qkv(
    const float* __restrict__ x,
    const float* __restrict__ Wq,
    const float* __restrict__ Wk,
    const float* __restrict__ Wv,
    unsigned short* __restrict__ QKVbf,
    unsigned short* __restrict__ Vt)
{
    __shared__ unsigned short Asb[64][72];
    __shared__ unsigned short Bsb[64][72];

    const int m0 = blockIdx.x * 64;
    const int n0 = blockIdx.y * 64;

    const float* Bp; float scale; int role;   // 0=Q 1=K 2=V
    if (n0 < NQ)            { Bp = Wq + (size_t)n0 * INF_;              scale = 0.125f; role = 0; }
    else if (n0 < NQ + NKV) { Bp = Wk + (size_t)(n0 - NQ) * INF_;       scale = 1.f;    role = 1; }
    else                    { Bp = Wv + (size_t)(n0 - NQ - NKV) * INF_; scale = 1.f;    role = 2; }

    const int tid = threadIdx.x;
    const int w = tid >> 6, lane = tid & 63;
    const int n = lane & 15, quad = lane >> 4;
    const int r0w = (w & 1) * 32, c0w = (w >> 1) * 32;
    const int sr = tid >> 2, skc = (tid & 3) * 16;   // 64 rows x 16-float chunk

    v4f acc[2][2];
#pragma unroll
    for (int rt = 0; rt < 2; rt++)
#pragma unroll
        for (int ct = 0; ct < 2; ct++) acc[rt][ct] = (v4f){0.f,0.f,0.f,0.f};

    const float* ap = x  + (size_t)(m0 + sr) * INF_ + skc;
    const float* bp = Bp + (size_t)sr * INF_ + skc;

    float4 pa[4], pb[4];
#pragma unroll
    for (int i = 0; i < 4; i++) {
        pa[i] = *(const float4*)(ap + 4 * i);
        pb[i] = *(const float4*)(bp + 4 * i);
    }

    for (int kb = 0; kb < INF_; kb += 64) {
        __syncthreads();
        *(uint4*)&Asb[sr][skc]     = make_uint4(f2bf2(pa[0].x,pa[0].y), f2bf2(pa[0].z,pa[0].w),
                                                f2bf2(pa[1].x,pa[1].y), f2bf2(pa[1].z,pa[1].w));
        *(uint4*)&Asb[sr][skc + 8] = make_uint4(f2bf2(pa[2].x,pa[2].y), f2bf2(pa[2].z,pa[2].w),
                                                f2bf2(pa[3].x,pa[3].y), f2bf2(pa[3].z,pa[3].w));
        *(uint4*)&Bsb[sr][skc]     = make_uint4(f2bf2(pb[0].x,pb[0].y), f2bf2(pb[0].z,pb[0].w),
                                                f2bf2(pb[1].x,pb[1].y), f2bf2(pb[1].z,pb[1].w));
        *(uint4*)&Bsb[sr][skc + 8] = make_uint4(f2bf2(pb[2].x,pb[2].y), f2bf2(pb[2].z,pb[2].w),
                                                f2bf2(pb[3].x,pb[3].y), f2bf2(pb[3].z,pb[3].w));
        __syncthreads();
        if (kb + 64 < INF_) {
#pragma unroll
            for (int i = 0; i < 4; i++) {
                pa[i] = *(const float4*)(ap + kb + 64 + 4 * i);
                pb[i] = *(const float4*)(bp + kb + 64 + 4 * i);
            }
        }
#pragma unroll
        for (int kk = 0; kk < 2; kk++) {
            v8s a0 = *(const v8s*)&Asb[r0w + n][kk * 32 + quad * 8];
            v8s a1 = *(const v8s*)&Asb[r0w + 16 + n][kk * 32 + quad * 8];
            v8s b0 = *(const v8s*)&Bsb[c0w + n][kk * 32 + quad * 8];
            v8s b1 = *(const v8s*)&Bsb[c0w + 16 + n][kk * 32 + quad * 8];
            acc[0][0] = __builtin_amdgcn_mfma_f32_16x16x32_bf16(a0, b0, acc[0][0], 0, 0, 0);
            acc[0][1] = __builtin_amdgcn_mfma_f32_16x16x32_bf16(a0, b1, acc[0][1], 0, 0, 0);
            acc[1][0] = __builtin_amdgcn_mfma_f32_16x16x32_bf16(a1, b0, acc[1][0], 0, 0, 0);
            acc[1][1] = __builtin_amdgcn_mfma_f32_16x16x32_bf16(a1, b1, acc[1][1], 0, 0, 0);
        }
    }

    if (role == 2) {
        // Vt[d][s]: lane holds 4 consecutive s -> b64 stores
#pragma unroll
        for (int rt = 0; rt < 2; rt++)
#pragma unroll
            for (int ct = 0; ct < 2; ct++) {
                const int vcol = n0 - NQ - NKV + c0w + ct * 16 + n;
                uint2 pk = make_uint2(f2bf2(acc[rt][ct][0], acc[rt][ct][1]),
                                      f2bf2(acc[rt][ct][2], acc[rt][ct][3]));
                *(uint2*)(Vt + (size_t)vcol * SEQ + m0 + r0w + rt * 16 + quad * 4) = pk;
            }
    } else {
#pragma unroll
        for (int rt = 0; rt < 2; rt++)
#pragma unroll
            for (int ct = 0; ct < 2; ct++)
#pragma unroll
                for (int reg = 0; reg < 4; reg++) {
                    const int row = m0 + r0w + rt * 16 + quad * 4 + reg;
                    const int col = n0 + c0w + ct * 16 + n;
                    QKVbf[(size_t)row * NQKV + col] = f2bf(acc[rt][ct][reg] * scale);
                }
    }
}

// ===========================================================================
// MFMA flash attention, S^T formulation (K·Q^T), max-free softmax.
// Block = 128 q-rows x head x g-pair; 4 waves x 32 rows.
// Balance: CU gets blocks bx and bx+256 (same per-round dispatch map);
// qi2 = gp ? 15-jb : jb makes their work sum constant (34 tile-iters).
// ===========================================================================
__global__ __launch_bounds__(256, 2) void attn_mfma(
    const unsigned short* __restrict__ QKVbf,
    const unsigned short* __restrict__ Vt,
    unsigned short* __restrict__ Oh0,
    unsigned short* __restrict__ Oh1)
{
    __shared__ unsigned short Qs [128][72];
    __shared__ unsigned short Ks [2][64][72];
    __shared__ unsigned short VsT[2][64][72];   // VsT[d][j]
    __shared__ unsigned short PsT[4][32][72];   // per-wave P[q][j]

    const int bx  = blockIdx.x;
    const int h   = bx & 15;
    const int jb  = (bx >> 4) & 15;
    const int gp  = bx >> 8;                    // 0 or 1
    const int qi2 = gp ? (15 - jb) : jb;        // complementary across rounds
    const int q0  = qi2 * 128;
    const int tid = threadIdx.x;
    const int w = tid >> 6, lane = tid & 63;
    const int n = lane & 15, quad = lane >> 4;
    const int r0 = w * 32;

    // stage Q (once): 128 rows x 64 d (pre-scaled by 1/8)
    {
        const int r = tid >> 1, c = (tid & 1) * 32;
        const unsigned short* src = QKVbf + (size_t)(q0 + r) * NQKV + h * DH + c;
        uint4 v0 = *(const uint4*)(src);
        uint4 v1 = *(const uint4*)(src + 8);
        uint4 v2 = *(const uint4*)(src + 16);
        uint4 v3 = *(const uint4*)(src + 24);
        *(uint4*)&Qs[r][c]      = v0;
        *(uint4*)&Qs[r][c + 8]  = v1;
        *(uint4*)&Qs[r][c + 16] = v2;
        *(uint4*)&Qs[r][c + 24] = v3;
    }
    __syncthreads();

    v8s qf[2][2];
#pragma unroll
    for (int qt = 0; qt < 2; qt++) {
        qf[qt][0] = *(const v8s*)&Qs[r0 + qt * 16 + n][quad * 8];
        qf[qt][1] = *(const v8s*)&Qs[r0 + qt * 16 + n][32 + quad * 8];
    }

    v4f Ofin[2][4];
#pragma unroll
    for (int qt = 0; qt < 2; qt++)
#pragma unroll
        for (int dt = 0; dt < 4; dt++) Ofin[qt][dt] = (v4f){0.f,0.f,0.f,0.f};

    const int ntile = 2 * qi2 + 2;
    const int krow = tid >> 2, kc = (tid & 3) * 16;
    const int vd   = tid >> 2, vj = (tid & 3) * 16;
    const v4f z = (v4f){0.f,0.f,0.f,0.f};

    for (int gg = 0; gg < 2; gg++) {
        const int g = gp * 2 + gg;
        float lst[2] = {0.f, 0.f};
        v4f Oacc[2][4];
#pragma unroll
        for (int qt = 0; qt < 2; qt++)
#pragma unroll
            for (int dt = 0; dt < 4; dt++) Oacc[qt][dt] = (v4f){0.f,0.f,0.f,0.f};

        const unsigned short* kbase = QKVbf + NQ + g * DH + kc;
        const unsigned short* vbase = Vt + (size_t)(g * DH + vd) * SEQ + vj;

        uint4 kr0 = *(const uint4*)(kbase + (size_t)krow * NQKV);
        uint4 kr1 = *(const uint4*)(kbase + (size_t)krow * NQKV + 8);
        uint4 vr0 = *(const uint4*)(vbase);
        uint4 vr1 = *(const uint4*)(vbase + 8);

        for (int tt = 0; tt < ntile; tt++) {
            const int buf = tt & 1;
            const int t0 = tt * 64;
            *(uint4*)&Ks[buf][krow][kc]     = kr0;
            *(uint4*)&Ks[buf][krow][kc + 8] = kr1;
            *(uint4*)&VsT[buf][vd][vj]      = vr0;
            *(uint4*)&VsT[buf][vd][vj + 8]  = vr1;
            if (tt + 1 < ntile) {
                const int t1 = (tt + 1) * 64;
                kr0 = *(const uint4*)(kbase + (size_t)(t1 + krow) * NQKV);
                kr1 = *(const uint4*)(kbase + (size_t)(t1 + krow) * NQKV + 8);
                vr0 = *(const uint4*)(vbase + t1);
                vr1 = *(const uint4*)(vbase + t1 + 8);
            }
            __syncthreads();

            const bool do0 = (t0 <= q0 + r0 + 15);
            const bool do1 = (t0 <= q0 + r0 + 31);
            if (do1) {
                // S^T = K·Q^T
                v4f sc[2][4];
#pragma unroll
                for (int jt = 0; jt < 4; jt++) {
                    v8s kf0 = *(const v8s*)&Ks[buf][jt * 16 + n][quad * 8];
                    v8s kf1 = *(const v8s*)&Ks[buf][jt * 16 + n][32 + quad * 8];
                    if (do0) {
                        v4f t = __builtin_amdgcn_mfma_f32_16x16x32_bf16(kf0, qf[0][0], z, 0, 0, 0);
                        sc[0][jt] = __builtin_amdgcn_mfma_f32_16x16x32_bf16(kf1, qf[0][1], t, 0, 0, 0);
                    }
                    v4f t1 = __builtin_amdgcn_mfma_f32_16x16x32_bf16(kf0, qf[1][0], z, 0, 0, 0);
                    sc[1][jt] = __builtin_amdgcn_mfma_f32_16x16x32_bf16(kf1, qf[1][1], t1, 0, 0, 0);
                }

                // mask (diagonal region only) + exp + per-lane l + P^T b64 write
#pragma unroll
                for (int qt = 0; qt < 2; qt++) {
                    if (qt == 0 && !do0) continue;
                    const int qg = q0 + r0 + qt * 16 + n;
                    if (t0 + 63 > q0 + r0 + qt * 16) {
#pragma unroll
                        for (int jt = 0; jt < 4; jt++) {
                            const int jg = t0 + jt * 16 + quad * 4;
#pragma unroll
                            for (int reg = 0; reg < 4; reg++)
                                sc[qt][jt][reg] = (jg + reg <= qg) ? sc[qt][jt][reg] : -INFINITY;
                        }
                    }
#pragma unroll
                    for (int jt = 0; jt < 4; jt++) {
                        float p0 = __expf(sc[qt][jt][0]);
                        float p1 = __expf(sc[qt][jt][1]);
                        float p2 = __expf(sc[qt][jt][2]);
                        float p3 = __expf(sc[qt][jt][3]);
                        lst[qt] += (p0 + p1) + (p2 + p3);
                        *(uint2*)&PsT[w][qt * 16 + n][jt * 16 + quad * 4] =
                            make_uint2(f2bf2(p0, p1), f2bf2(p2, p3));
                    }
                }

                // PV: O^T = V^T · P^T (per-wave PsT, no barrier)
                v8s pf[2][2];
                if (do0) {
                    pf[0][0] = *(const v8s*)&PsT[w][n][quad * 8];
                    pf[0][1] = *(const v8s*)&PsT[w][n][32 + quad * 8];
                }
                pf[1][0] = *(const v8s*)&PsT[w][16 + n][quad * 8];
                pf[1][1] = *(const v8s*)&PsT[w][16 + n][32 + quad * 8];
#pragma unroll
                for (int dt = 0; dt < 4; dt++) {
                    v8s vf0 = *(const v8s*)&VsT[buf][dt * 16 + n][quad * 8];
                    v8s vf1 = *(const v8s*)&VsT[buf][dt * 16 + n][32 + quad * 8];
                    if (do0) {
                        Oacc[0][dt] = __builtin_amdgcn_mfma_f32_16x16x32_bf16(vf0, pf[0][0], Oacc[0][dt], 0, 0, 0);
                        Oacc[0][dt] = __builtin_amdgcn_mfma_f32_16x16x32_bf16(vf1, pf[0][1], Oacc[0][dt], 0, 0, 0);
                    }
                    Oacc[1][dt] = __builtin_amdgcn_mfma_f32_16x16x32_bf16(vf0, pf[1][0], Oacc[1][dt], 0, 0, 0);
                    Oacc[1][dt] = __builtin_amdgcn_mfma_f32_16x16x32_bf16(vf1, pf[1][1], Oacc[1][dt], 0, 0, 0);
                }
            }
        }

#pragma unroll
        for (int qt = 0; qt < 2; qt++) {
            float L = lst[qt];
            L += __shfl_xor(L, 16);
            L += __shfl_xor(L, 32);
            const float inv = 0.25f / L;
#pragma unroll
            for (int dt = 0; dt < 4; dt++)
#pragma unroll
                for (int reg = 0; reg < 4; reg++)
                    Ofin[qt][dt][reg] += Oacc[qt][dt][reg] * inv;
        }
    }

    unsigned short* Ohp = gp ? Oh1 : Oh0;
#pragma unroll
    for (int qt = 0; qt < 2; qt++) {
        const int row = q0 + r0 + qt * 16 + n;
        unsigned short* dst = Ohp + (size_t)row * NQ + h * DH + quad * 4;
#pragma unroll
        for (int dt = 0; dt < 4; dt++) {
            uint2 pk = make_uint2(f2bf2(Ofin[qt][dt][0], Ofin[qt][dt][1]),
                                  f2bf2(Ofin[qt][dt][2], Ofin[qt][dt][3]));
            *(uint2*)(dst + dt * 16) = pk;
        }
    }
}

// ===========================================================================
// GEMM 2 (MFMA): out[s][o] = sum_j (Oh0+Oh1)[s][j] * Wo[o][j]. fp32 out.
// 64x64 tile, BK=64 (16 iters), register prefetch. Grid 32x8 = 256 blocks.
// ===========================================================================
__global__ __launch_bounds__(256, 4) void gemm_out(
    const unsigned short* __restrict__ Oh0,
    const unsigned short* __restrict__ Oh1,
    const float* __restrict__ Wo,
    float* __restrict__ C)
{
    __shared__ unsigned short Asb[64][72];
    __shared__ unsigned short Bsb[64][72];

    const int m0 = blockIdx.x * 64;
    const int n0 = blockIdx.y * 64;
    const int tid = threadIdx.x;
    const int w = tid >> 6, lane = tid & 63;
    const int n = lane & 15, quad = lane >> 4;
    const int r0w = (w & 1) * 32, c0w = (w >> 1) * 32;
    const int sr = tid >> 2, skc = (tid & 3) * 16;   // staging: row, 16-elem chunk

    v4f acc[2][2];
#pragma unroll
    for (int rt = 0; rt < 2; rt++)
#pragma unroll
        for (int ct = 0; ct < 2; ct++) acc[rt][ct] = (v4f){0.f,0.f,0.f,0.f};

    const unsigned short* a0p = Oh0 + (size_t)(m0 + sr) * NQ + skc;
    const unsigned short* a1p = Oh1 + (size_t)(m0 + sr) * NQ + skc;
    const float* bp = Wo + (size_t)(n0 + sr) * NQ + skc;

    uint4 ua0 = *(const uint4*)(a0p),     ua1 = *(const uint4*)(a0p + 8);
    uint4 ub0 = *(const uint4*)(a1p),     ub1 = *(const uint4*)(a1p + 8);
    float4 pb[4];
#pragma unroll
    for (int i = 0; i < 4; i++) pb[i] = *(const float4*)(bp + 4 * i);

    for (int kb = 0; kb < NQ; kb += 64) {
        __syncthreads();
        *(uint4*)&Asb[sr][skc]     = make_uint4(addbf2(ua0.x, ub0.x), addbf2(ua0.y, ub0.y),
                                                addbf2(ua0.z, ub0.z), addbf2(ua0.w, ub0.w));
        *(uint4*)&Asb[sr][skc + 8] = make_uint4(addbf2(ua1.x, ub1.x), addbf2(ua1.y, ub1.y),
                                                addbf2(ua1.z, ub1.z), addbf2(ua1.w, ub1.w));
        *(uint4*)&Bsb[sr][skc]     = make_uint4(f2bf2(pb[0].x,pb[0].y), f2bf2(pb[0].z,pb[0].w),
                                                f2bf2(pb[1].x,pb[1].y), f2bf2(pb[1].z,pb[1].w));
        *(uint4*)&Bsb[sr][skc + 8] = make_uint4(f2bf2(pb[2].x,pb[2].y), f2bf2(pb[2].z,pb[2].w),
                                                f2bf2(pb[3].x,pb[3].y), f2bf2(pb[3].z,pb[3].w));
        __syncthreads();
        if (kb + 64 < NQ) {
            ua0 = *(const uint4*)(a0p + kb + 64);
            ua1 = *(const uint4*)(a0p + kb + 64 + 8);
            ub0 = *(const uint4*)(a1p + kb + 64);
            ub1 = *(const uint4*)(a1p + kb + 64 + 8);
#pragma unroll
            for (int i = 0; i < 4; i++) pb[i] = *(const float4*)(bp + kb + 64 + 4 * i);
        }
#pragma unroll
        for (int kk = 0; kk < 2; kk++) {
            v8s a0 = *(const v8s*)&Asb[r0w + n][kk * 32 + quad * 8];
            v8s a1 = *(const v8s*)&Asb[r0w + 16 + n][kk * 32 + quad * 8];
            v8s b0 = *(const v8s*)&Bsb[c0w + n][kk * 32 + quad * 8];
            v8s b1 = *(const v8s*)&Bsb[c0w + 16 + n][kk * 32 + quad * 8];
            acc[0][0] = __builtin_amdgcn_mfma_f32_16x16x32_bf16(a0, b0, acc[0][0], 0, 0, 0);
            acc[0][1] = __builtin_amdgcn_mfma_f32_16x16x32_bf16(a0, b1, acc[0][1], 0, 0, 0);
            acc[1][0] = __builtin_amdgcn_mfma_f32_16x16x32_bf16(a1, b0, acc[1][0], 0, 0, 0);
            acc[1][1] = __builtin_amdgcn_mfma_f32_16x16x32_bf16(a1, b1, acc[1][1], 0, 0, 0);
        }
    }

#pragma unroll
    for (int rt = 0; rt < 2; rt++)
#pragma unroll
        for (int ct = 0; ct < 2; ct++)
#pragma unroll
            for (int reg = 0; reg < 4; reg++) {
                const int row = m0 + r0w + rt * 16 + quad * 4 + reg;
                const int col = n0 + c0w + ct * 16 + n;
                C[(size_t)row * OUTD + col] = acc[rt][ct][reg];
            }
}

// ===========================================================================
extern "C" void kernel_launch(void* const* d_in, const int* in_sizes, int n_in,
                              void* d_out, int out_size, void* d_ws, size_t ws_size,
                              hipStream_t stream) {
    const float* x  = (const float*)d_in[0];
    const float* Wq = (const float*)d_in[1];
    const float* Wk = (const float*)d_in[2];
    const float* Wv = (const float*)d_in[3];
    const float* Wo = (const float*)d_in[4];
    float* out = (float*)d_out;

    // ws: QKVbf bf16 [2048][1536] @0; Vt bf16 [256][2048] @6291456;
    //     Oh0/Oh1 bf16 [2048][1024] @7340032 / @11534336
    char* base = (char*)d_ws;
    unsigned short* QKVbf = (unsigned short*)(base);
    unsigned short* Vt    = (unsigned short*)(base + 6291456);
    unsigned short* Oh0   = (unsigned short*)(base + 7340032);
    unsigned short* Oh1   = (unsigned short*)(base + 11534336);

    dim3 blk(256);
    gemm_qkv<<<dim3(SEQ / 64, NQKV / 64), blk, 0, stream>>>(x, Wq, Wk, Wv, QKVbf, Vt);
    attn_mfma<<<dim3(512), blk, 0, stream>>>(QKVbf, Vt, Oh0, Oh1);
    gemm_out<<<dim3(SEQ / 64, OUTD / 64), blk, 0, stream>>>(Oh0, Oh1, Wo, out);
}